// Round 16
// baseline (361.386 us; speedup 1.0000x reference)
//
#include <hip/hip_runtime.h>

typedef __bf16 bf16x8 __attribute__((ext_vector_type(8)));
typedef float f32x4 __attribute__((ext_vector_type(4)));
typedef unsigned int u32x4 __attribute__((ext_vector_type(4)));
typedef unsigned short u16x4 __attribute__((ext_vector_type(4)));
typedef unsigned short u16x8 __attribute__((ext_vector_type(8)));

#define SEQ_T 4096
#define DMODEL 1024
#define HEADS 16
#define DKH 64
#define MTOK 16384  // N*T rows

#define AS1 __attribute__((address_space(1)))
#define AS3 __attribute__((address_space(3)))

__device__ __forceinline__ unsigned short f2bf(float f) {
  unsigned u = __builtin_bit_cast(unsigned int, f);
  u += 0x7FFFu + ((u >> 16) & 1u);
  return (unsigned short)(u >> 16);
}
__device__ __forceinline__ float bf2f(unsigned short h) {
  unsigned u = ((unsigned)h) << 16;
  return __builtin_bit_cast(float, u);
}
__device__ __forceinline__ void gload16(const unsigned short* g, unsigned short* l) {
  __builtin_amdgcn_global_load_lds((const AS1 unsigned int*)(g),
                                   (AS3 unsigned int*)(l), 16, 0, 0);
}

// ---- fp32 -> bf16, coalesced: 16B/lane loads, 8B/lane stores ----
__device__ __forceinline__ void cvt_block(const float* __restrict__ x,
                                          unsigned short* __restrict__ y,
                                          size_t b, int tid) {
  f32x4 a0 = *(const f32x4*)(x + b + tid * 4);
  f32x4 a1 = *(const f32x4*)(x + b + 1024 + tid * 4);
  u16x4 o0, o1;
#pragma unroll
  for (int j = 0; j < 4; ++j) {
    o0[j] = f2bf(a0[j]);
    o1[j] = f2bf(a1[j]);
  }
  *(u16x4*)(y + b + tid * 4) = o0;
  *(u16x4*)(y + b + 1024 + tid * 4) = o1;
}

__global__ void __launch_bounds__(256) k_cvt(const float* __restrict__ x,
                                             unsigned short* __restrict__ y) {
  cvt_block(x, y, (size_t)blockIdx.x * 2048, threadIdx.x);
}

// ---- upfront cvt of x_q/x_v only (x_k consumed as fp32 directly) ----
__global__ void __launch_bounds__(256) k_cvt2(const float* __restrict__ xq,
                                              const float* __restrict__ xv,
                                              unsigned short* __restrict__ oq,
                                              unsigned short* __restrict__ ov) {
  const int which = blockIdx.x >> 13;
  const float* x = which ? xv : xq;
  unsigned short* y = which ? ov : oq;
  cvt_block(x, y, (size_t)(blockIdx.x & 8191) * 2048, threadIdx.x);
}

// ---------------- W (K x N) fp32 -> Wt (N x K) bf16 ----------------
__global__ void __launch_bounds__(256) k_wtrans(const float* __restrict__ W,
                                                unsigned short* __restrict__ Wt,
                                                int K, int N) {
  __shared__ float tile[32][33];
  int bn = blockIdx.x * 32, bk = blockIdx.y * 32;
  int tx = threadIdx.x, ty = threadIdx.y;  // 32 x 8
#pragma unroll
  for (int j = 0; j < 32; j += 8)
    tile[ty + j][tx] = W[(size_t)(bk + ty + j) * N + bn + tx];
  __syncthreads();
#pragma unroll
  for (int j = 0; j < 32; j += 8)
    Wt[(size_t)(bn + ty + j) * K + bk + tx] = f2bf(tile[tx][ty + j]);
}

// ------- bf16 NT GEMM (R2 core + BK=64 swizzle + chunked XCD remap) -------
// C = A*Bt^T + bias.  SCORE=1: fused alpha scores.  FUSEA=1: per-n Bt/bias
// + fused q-add.  Chunked XCD remap: XCD x owns 16 consecutive row-panels x
// all 8 column blocks for A-panel L2 locality.
#define BM 128
#define BN 128
#define BK 64

template <int OBF, int SCORE, int FUSEA>
__global__ void __launch_bounds__(256, 2)
k_gemm(const unsigned short* __restrict__ A, const unsigned short* __restrict__ Bt,
       const float* __restrict__ bias, void* __restrict__ C,
       const int* __restrict__ mask, const float* __restrict__ swt,
       float* __restrict__ sbuf, const unsigned short* __restrict__ qadd,
       int M, int N, int K) {
  __shared__ unsigned short As[BM * BK];
  __shared__ unsigned short Bs[BN * BK];
  const int tid = threadIdx.x;
  const int lane = tid & 63, wid = tid >> 6;
  const int wr = wid >> 1, wc = wid & 1;
  const int l15 = lane & 15, l4 = lane >> 4;

  // bijective chunked XCD remap (nwg = 8*128 = 1024, %8 == 0)
  const int nwg = gridDim.x * gridDim.y;
  const int flat = blockIdx.x + blockIdx.y * gridDim.x;
  const int rm = (flat & 7) * (nwg >> 3) + (flat >> 3);
  const int bx = rm % gridDim.x, by = rm / gridDim.x;
  const int bm = by * BM, bn = bx * BN;

  const unsigned short* Btn = FUSEA ? Bt + ((size_t)(bm >> 12) << 20) : Bt;
  const float* biasn = FUSEA ? bias + ((bm >> 12) << 10) : bias;

  f32x4 acc[4][4];
#pragma unroll
  for (int i = 0; i < 4; ++i)
#pragma unroll
    for (int j = 0; j < 4; ++j)
#pragma unroll
      for (int e = 0; e < 4; ++e) acc[i][j][e] = 0.f;

  // staging: one gload16 covers 8 rows x 128B; lane l -> row +(l>>3),
  // source chunk (l&7)^(l>>3) (pre-swizzled; LDS slot is linear l&7).
  const int sgr = lane >> 3;
  const int sgc = (lane & 7) ^ sgr;

  for (int kt = 0; kt < K; kt += BK) {
    __syncthreads();  // previous tile consumed
#pragma unroll
    for (int j = 0; j < 4; ++j) {
      int rb = wid * 32 + j * 8;
      gload16(A + (size_t)(bm + rb + sgr) * K + kt + sgc * 8, As + rb * BK);
    }
#pragma unroll
    for (int j = 0; j < 4; ++j) {
      int rb = wid * 32 + j * 8;
      gload16(Btn + (size_t)(bn + rb + sgr) * K + kt + sgc * 8, Bs + rb * BK);
    }
    __syncthreads();  // drain -> tile resident
#pragma unroll
    for (int kh = 0; kh < 2; ++kh) {
      bf16x8 af[4], bfr[4];
#pragma unroll
      for (int m = 0; m < 4; ++m) {
        int ra = wr * 64 + m * 16 + l15;
        int sl = (kh * 4 + l4) ^ (ra & 7);
        af[m] = *(const bf16x8*)(As + ra * BK + sl * 8);
      }
#pragma unroll
      for (int n = 0; n < 4; ++n) {
        int rb = wc * 64 + n * 16 + l15;
        int sl = (kh * 4 + l4) ^ (rb & 7);
        bfr[n] = *(const bf16x8*)(Bs + rb * BK + sl * 8);
      }
#pragma unroll
      for (int m = 0; m < 4; ++m)
#pragma unroll
        for (int n = 0; n < 4; ++n)
          acc[m][n] = __builtin_amdgcn_mfma_f32_16x16x32_bf16(af[m], bfr[n],
                                                              acc[m][n], 0, 0, 0);
    }
  }

  const int crow = bm + wr * 64 + l4 * 4;
  const int ccol = bn + wc * 64 + l15;

  float pacc[4][4];
  const float* wrow = nullptr;
  if (SCORE == 1) wrow = swt;
  if (SCORE) {
#pragma unroll
    for (int m = 0; m < 4; ++m)
#pragma unroll
      for (int e = 0; e < 4; ++e) pacc[m][e] = 0.f;
  }

#pragma unroll
  for (int m = 0; m < 4; ++m)
#pragma unroll
    for (int n = 0; n < 4; ++n) {
      int c = ccol + n * 16;
      float bj = biasn[c];
      float wg = SCORE ? wrow[n * 16 + l15] : 0.f;
#pragma unroll
      for (int e = 0; e < 4; ++e) {
        int r = crow + m * 16 + e;
        float v = acc[m][n][e] + bj;
        if (FUSEA) v += bf2f(qadd[(size_t)r * N + c]);
        if (SCORE) pacc[m][e] += v * wg;
        if (OBF)
          ((unsigned short*)C)[(size_t)r * N + c] = f2bf(v);
        else
          ((float*)C)[(size_t)r * N + c] = v;
      }
    }

  if (SCORE) {
#pragma unroll
    for (int m = 0; m < 4; ++m)
#pragma unroll
      for (int e = 0; e < 4; ++e) {
        float p = pacc[m][e];
        p += __shfl_xor(p, 1);
        p += __shfl_xor(p, 2);
        p += __shfl_xor(p, 4);
        p += __shfl_xor(p, 8);
        if (l15 == 0) {
          int r = crow + m * 16 + e;
          int t = r & (SEQ_T - 1), n = r >> 12;
          float sc = p * 0.125f;
          if (mask[n * SEQ_T + t] == 0) sc = -3.0e38f;
          sbuf[((size_t)n * HEADS + bx * 2 + wc) * SEQ_T + t] = sc;
        }
      }
  }
}

// ---- per-(n,h) softmax stats over T=4096 (merged max+sum, 64 blocks) ----
__global__ void __launch_bounds__(256) k_softmax(const float* __restrict__ s,
                                                 float* __restrict__ mxo,
                                                 float* __restrict__ invo) {
  __shared__ float red[4];
  const int tid = threadIdx.x, lane = tid & 63, wid = tid >> 6;
  const float* sb = s + (size_t)blockIdx.x * SEQ_T;
  float m = -3.4e38f;
  for (int t = tid; t < SEQ_T; t += 256) m = fmaxf(m, sb[t]);
#pragma unroll
  for (int o = 1; o < 64; o <<= 1) m = fmaxf(m, __shfl_xor(m, o));
  if (lane == 0) red[wid] = m;
  __syncthreads();
  m = fmaxf(fmaxf(red[0], red[1]), fmaxf(red[2], red[3]));
  __syncthreads();
  float sum = 0.f;
  for (int t = tid; t < SEQ_T; t += 256) sum += __expf(sb[t] - m);
#pragma unroll
  for (int o = 1; o < 64; o <<= 1) sum += __shfl_xor(sum, o);
  if (lane == 0) red[wid] = sum;
  __syncthreads();
  if (tid == 0) {
    mxo[blockIdx.x] = m;
    invo[blockIdx.x] = 1.f / (red[0] + red[1] + red[2] + red[3]);
  }
}

// ---- alpha weighted sum: pbuf[nh,chunk,:] = sum_t w[t]*q[n,t,h,:] ----
__global__ void __launch_bounds__(256) k_wsum(const unsigned short* __restrict__ X,
                                              const float* __restrict__ s,
                                              const float* __restrict__ mxv,
                                              const float* __restrict__ invv,
                                              float* __restrict__ pbuf) {
  __shared__ float part[16][64];
  const int nh = blockIdx.x >> 4, chunk = blockIdx.x & 15;
  const int n = nh >> 4, h = nh & 15;
  const int tid = threadIdx.x, lane = tid & 63, wid = tid >> 6;
  const int tsub = lane >> 4, dl = lane & 15;
  const float mx = mxv[nh], inv = invv[nh];
  const float* sb = s + (size_t)nh * SEQ_T + chunk * 256;
  const size_t base = ((size_t)n * SEQ_T + chunk * 256) * DMODEL + h * DKH + dl * 4;
  f32x4 acc = {0.f, 0.f, 0.f, 0.f};
  for (int t = wid * 4 + tsub; t < 256; t += 16) {
    float w = __expf(sb[t] - mx) * inv;
    u16x4 xv = *(const u16x4*)(X + base + (size_t)t * DMODEL);
    acc[0] += w * bf2f(xv[0]);
    acc[1] += w * bf2f(xv[1]);
    acc[2] += w * bf2f(xv[2]);
    acc[3] += w * bf2f(xv[3]);
  }
  int g = wid * 4 + tsub;
#pragma unroll
  for (int e = 0; e < 4; ++e) part[g][dl * 4 + e] = acc[e];
  __syncthreads();
  if (tid < 64) {
    float v = 0.f;
#pragma unroll
    for (int gg = 0; gg < 16; ++gg) v += part[gg][tid];
    pbuf[(size_t)blockIdx.x * 64 + tid] = v;
  }
}

// ---- merged fin+wks+bks: gq from pbuf; wv=gq*bw; WksF=Wk·wv (fp32); bks ----
__global__ void __launch_bounds__(256) k_wksb(const float* __restrict__ Wk,
                                              const float* __restrict__ bk,
                                              const float* __restrict__ pbuf,
                                              const float* __restrict__ bw,
                                              float* __restrict__ gq,
                                              float* __restrict__ WksF,
                                              float* __restrict__ bks) {
  const int nh = blockIdx.x, tid = threadIdx.x;
  const int h = nh & 15;
  __shared__ float wvs[64];
  if (tid < 64) {
    float v = 0.f;
#pragma unroll
    for (int c = 0; c < 16; ++c) v += pbuf[((size_t)nh * 16 + c) * 64 + tid];
    gq[(size_t)nh * 64 + tid] = v;
    wvs[tid] = v * bw[tid];
  }
  __syncthreads();
  int c0 = tid * 4;
  f32x4 o;
#pragma unroll
  for (int i = 0; i < 4; ++i) {
    int c = c0 + i;
    const float* wr = Wk + (size_t)c * DMODEL + h * DKH;
    float acc = 0.f;
#pragma unroll
    for (int dd = 0; dd < 64; dd += 4) {
      f32x4 w4 = *(const f32x4*)(wr + dd);
      acc += w4[0] * wvs[dd] + w4[1] * wvs[dd + 1] + w4[2] * wvs[dd + 2] +
             w4[3] * wvs[dd + 3];
    }
    o[i] = acc;
  }
  *(f32x4*)(WksF + (size_t)nh * DMODEL + c0) = o;
  if (tid < 64) {
    float p = bk[h * 64 + tid] * wvs[tid];
#pragma unroll
    for (int ofs = 1; ofs < 64; ofs <<= 1) p += __shfl_xor(p, ofs);
    if (tid == 0) bks[nh] = p;
  }
}

// ---- beta scores from fp32 x_k directly: one wave per token row ----
// lane = (head h = lane>>2, sub = lane&3); dot over 1024 dims, 4-lane reduce.
__global__ void __launch_bounds__(256) k_scoref(const float* __restrict__ xk,
                                                const float* __restrict__ WksF,
                                                const float* __restrict__ bks,
                                                const int* __restrict__ mask,
                                                float* __restrict__ sbuf) {
  const int tid = threadIdx.x, lane = tid & 63, wid = tid >> 6;
  const size_t nt = (size_t)blockIdx.x * 4 + wid;
  const int n = (int)(nt >> 12), t = (int)(nt & 4095);
  const int h = lane >> 2, sub = lane & 3;
  const float* xr = xk + nt * DMODEL;
  const float* wr = WksF + ((size_t)n * HEADS + h) * DMODEL;
  float p = 0.f;
#pragma unroll
  for (int j = 0; j < 16; ++j) {
    int c = j * 64 + sub * 16;
#pragma unroll
    for (int k = 0; k < 4; ++k) {
      f32x4 xv = *(const f32x4*)(xr + c + k * 4);
      f32x4 wv = *(const f32x4*)(wr + c + k * 4);
      p += xv[0] * wv[0] + xv[1] * wv[1] + xv[2] * wv[2] + xv[3] * wv[3];
    }
  }
  p += __shfl_xor(p, 1);
  p += __shfl_xor(p, 2);
  if (sub == 0) {
    float sc = (p + bks[n * HEADS + h]) * 0.125f;
    if (mask[n * SEQ_T + t] == 0) sc = -3.0e38f;
    sbuf[((size_t)n * HEADS + h) * SEQ_T + t] = sc;
  }
}

// ---- beta-weighted pooling of fp32 x_k: part[(n*64+tc)][h][c] ----
__global__ void __launch_bounds__(256) k_bwsum(const float* __restrict__ xk,
                                               const float* __restrict__ s,
                                               const float* __restrict__ smx,
                                               const float* __restrict__ sinv,
                                               float* __restrict__ part) {
  __shared__ float eb[16][64];
  const int tc = blockIdx.x, n = blockIdx.y, tid = threadIdx.x;
#pragma unroll
  for (int i = 0; i < 4; ++i) {
    int idx = i * 256 + tid;
    int h = idx >> 6, t = idx & 63;
    int nh = n * 16 + h;
    eb[h][t] = __expf(s[(size_t)nh * SEQ_T + tc * 64 + t] - smx[nh]) * sinv[nh];
  }
  __syncthreads();
  const int c0 = tid * 4;
  f32x4 acc[16];
#pragma unroll
  for (int h = 0; h < 16; ++h)
#pragma unroll
    for (int e = 0; e < 4; ++e) acc[h][e] = 0.f;
  const float* xb = xk + ((size_t)n * SEQ_T + tc * 64) * DMODEL + c0;
  for (int t = 0; t < 64; ++t) {
    f32x4 x = *(const f32x4*)(xb + (size_t)t * DMODEL);
#pragma unroll
    for (int h = 0; h < 16; ++h) {
      float w = eb[h][t];
      acc[h][0] += w * x[0];
      acc[h][1] += w * x[1];
      acc[h][2] += w * x[2];
      acc[h][3] += w * x[3];
    }
  }
#pragma unroll
  for (int h = 0; h < 16; ++h)
    *(f32x4*)(part + (((size_t)(n * 64 + tc)) * 16 + h) * DMODEL + c0) = acc[h];
}

// ---- merged gkr+wrgb: pooled=Σpart; gk=gq*(pooled·WkT+bk) (smem);
//      WrgT[nh][d][dd]=gk[dd]*Wr[dd][d]; bcomb=bv·Wrg+br ----
__global__ void __launch_bounds__(256) k_gkrw(const float* __restrict__ part,
                                              const unsigned short* __restrict__ WkT,
                                              const float* __restrict__ bk,
                                              const float* __restrict__ gq,
                                              const float* __restrict__ Wr,
                                              const float* __restrict__ bv,
                                              const float* __restrict__ br,
                                              unsigned short* __restrict__ WrgT,
                                              float* __restrict__ bcomb) {
  __shared__ float pl[DMODEL];
  __shared__ float gks[64];
  __shared__ float wl[4096];
  const int nh = blockIdx.x, tid = threadIdx.x;
  const int n = nh >> 4, h = nh & 15;
  const int c0 = tid * 4;
  f32x4 a4 = {0.f, 0.f, 0.f, 0.f};
  for (int tc = 0; tc < 64; ++tc) {
    f32x4 p = *(const f32x4*)(part + (((size_t)(n * 64 + tc)) * 16 + h) * DMODEL + c0);
    a4[0] += p[0]; a4[1] += p[1]; a4[2] += p[2]; a4[3] += p[3];
  }
#pragma unroll
  for (int e = 0; e < 4; ++e) pl[c0 + e] = a4[e];
  __syncthreads();
  if (tid < 64) {
    const unsigned short* wr = WkT + (size_t)(h * 64 + tid) * DMODEL;
    float acc = 0.f;
    for (int c = 0; c < DMODEL; c += 8) {
      u16x8 w = *(const u16x8*)(wr + c);
#pragma unroll
      for (int j = 0; j < 8; ++j) acc += pl[c + j] * bf2f(w[j]);
    }
    gks[tid] = gq[(size_t)nh * 64 + tid] * (acc + bk[h * 64 + tid]);
  }
  __syncthreads();
#pragma unroll
  for (int i = 0; i < 16; ++i) {
    int idx = i * 256 + tid;
    int d = idx >> 6, dd = idx & 63;
    float v = gks[dd] * Wr[dd * 64 + d];
    wl[idx] = v;
    WrgT[(size_t)nh * 4096 + idx] = f2bf(v);
  }
  __syncthreads();
  if (tid < 64) {
    float acc = br[tid];
#pragma unroll
    for (int dd = 0; dd < 64; ++dd) acc += bv[h * 64 + dd] * wl[tid * 64 + dd];
    bcomb[(size_t)n * DMODEL + h * 64 + tid] = acc;
  }
}

// ---- WcombT[n][h*64+d][r] = sum_dd WrgT[nh][d][dd] * WvN[r][h*64+dd] ----
#define LDW 72
__global__ void __launch_bounds__(256) k_wcomb(const unsigned short* __restrict__ WrgT,
                                               const unsigned short* __restrict__ WvN,
                                               unsigned short* __restrict__ WcombT) {
  __shared__ unsigned short Wg[64 * LDW];
  __shared__ unsigned short Vv[128 * LDW];
  const int rc = blockIdx.x, nh = blockIdx.y;
  const int n = nh >> 4, h = nh & 15;
  const int tid = threadIdx.x, lane = tid & 63, wid = tid >> 6;
  const int l15 = lane & 15, l4 = lane >> 4;
#pragma unroll
  for (int i = 0; i < 2; ++i) {
    int v = i * 256 + tid;
    int d = v >> 3, k8 = v & 7;
    *(u16x8*)(Wg + d * LDW + k8 * 8) =
        *(const u16x8*)(WrgT + (size_t)nh * 4096 + d * 64 + k8 * 8);
  }
#pragma unroll
  for (int i = 0; i < 4; ++i) {
    int v = i * 256 + tid;
    int r = v >> 3, k8 = v & 7;
    *(u16x8*)(Vv + r * LDW + k8 * 8) =
        *(const u16x8*)(WvN + (size_t)(rc * 128 + r) * DMODEL + h * 64 + k8 * 8);
  }
  __syncthreads();
  f32x4 acc[8];
#pragma unroll
  for (int ct = 0; ct < 8; ++ct)
#pragma unroll
    for (int e = 0; e < 4; ++e) acc[ct][e] = 0.f;
#pragma unroll
  for (int ks = 0; ks < 2; ++ks) {
    bf16x8 af = *(const bf16x8*)(Wg + (wid * 16 + l15) * LDW + ks * 32 + l4 * 8);
#pragma unroll
    for (int ct = 0; ct < 8; ++ct) {
      bf16x8 bf = *(const bf16x8*)(Vv + (ct * 16 + l15) * LDW + ks * 32 + l4 * 8);
      acc[ct] = __builtin_amdgcn_mfma_f32_16x16x32_bf16(af, bf, acc[ct], 0, 0, 0);
    }
  }
  unsigned short* out = WcombT + ((size_t)n << 20);
#pragma unroll
  for (int ct = 0; ct < 8; ++ct)
#pragma unroll
    for (int e = 0; e < 4; ++e) {
      int d = h * 64 + wid * 16 + l4 * 4 + e;
      int r = rc * 128 + ct * 16 + l15;
      out[(size_t)d * DMODEL + r] = f2bf(acc[ct][e]);
    }
}

extern "C" void kernel_launch(void* const* d_in, const int* in_sizes, int n_in,
                              void* d_out, int out_size, void* d_ws, size_t ws_size,
                              hipStream_t stream) {
  const float* x_k = (const float*)d_in[0];
  const float* x_v = (const float*)d_in[1];
  const float* x_q = (const float*)d_in[2];
  const int* mask = (const int*)d_in[3];
  const float* Wk = (const float*)d_in[4];
  const float* bk = (const float*)d_in[5];
  const float* Wv = (const float*)d_in[6];
  const float* bv = (const float*)d_in[7];
  const float* Wq = (const float*)d_in[8];
  const float* bq = (const float*)d_in[9];
  const float* alpha_w = (const float*)d_in[10];
  const float* beta_w = (const float*)d_in[11];
  const float* Wr = (const float*)d_in[12];
  const float* br = (const float*)d_in[13];
  const float* Wfc = (const float*)d_in[14];
  const float* bfc = (const float*)d_in[15];

  // d_out layout during pipeline: [0:32MB) q bf16 (written by Q GEMM),
  // [32:64MB) x_v bf16 (written by cvt2).  Both dead before final GEMM write.
  unsigned short* qbf = (unsigned short*)d_out;
  unsigned short* xvb = (unsigned short*)d_out + (size_t)MTOK * DMODEL;

  char* ws = (char*)d_ws;
  const size_t MB = 1024 * 1024;
  unsigned short* xst = (unsigned short*)(ws);                 // 32 MB: x_q bf16
  unsigned short* abuf = (unsigned short*)(ws + 32 * MB);      // 32 MB: A matrix
  unsigned short* WqT = (unsigned short*)(ws + 64 * MB);       // 2 MB
  unsigned short* WkT = WqT + (size_t)DMODEL * DMODEL;         // 2 MB
  unsigned short* WfT = WkT + (size_t)DMODEL * DMODEL;         // 2 MB
  unsigned short* WvN = WfT + (size_t)DMODEL * DMODEL;         // 2 MB
  unsigned short* WcombT = WvN + (size_t)DMODEL * DMODEL;      // 8 MB
  unsigned short* WrgT = WcombT + (size_t)4 * DMODEL * DMODEL; // 512 KB
  float* WksF = (float*)(WrgT + (size_t)64 * 4096);            // 256 KB fp32
  float* part = WksF + (size_t)64 * DMODEL;                    // 16 MB
  float* sbuf = part + (size_t)256 * 16 * DMODEL;              // 1 MB
  float* pbuf = sbuf + (size_t)64 * SEQ_T;                     // 256 KB
  float* smx = pbuf + 1024 * 64;
  float* sinv = smx + 64;
  float* gq = sinv + 64;
  float* bks = gq + 4096;
  float* bcomb = bks + 64;

  dim3 tb(32, 8);
  dim3 tg(DMODEL / 32, DMODEL / 32);
  k_wtrans<<<tg, tb, 0, stream>>>(Wq, WqT, DMODEL, DMODEL);
  k_wtrans<<<tg, tb, 0, stream>>>(Wk, WkT, DMODEL, DMODEL);
  k_wtrans<<<tg, tb, 0, stream>>>(Wfc, WfT, DMODEL, DMODEL);
  k_cvt<<<512, 256, 0, stream>>>(Wv, WvN);

  // upfront conversions: x_q -> xst, x_v -> d_out upper half
  k_cvt2<<<2 * 8192, 256, 0, stream>>>(x_q, x_v, xst, xvb);

  dim3 ggrid(DMODEL / BN, MTOK / BM);  // (8, 128)

  // ---- Q projection (+fused alpha scores), q -> bf16 in d_out ----
  k_gemm<1, 1, 0><<<ggrid, 256, 0, stream>>>(xst, WqT, bq, (void*)qbf, mask,
                                             alpha_w, sbuf, nullptr,
                                             MTOK, DMODEL, DMODEL);
  // alpha pooling -> gq; then WksF/bks (merged)
  k_softmax<<<64, 256, 0, stream>>>(sbuf, smx, sinv);
  k_wsum<<<1024, 256, 0, stream>>>(qbf, sbuf, smx, sinv, pbuf);
  k_wksb<<<64, 256, 0, stream>>>(Wk, bk, pbuf, beta_w, gq, WksF, bks);

  // ---- K path on fp32 x_k (k never materialized, no bf16 copy) ----
  k_scoref<<<MTOK / 4, 256, 0, stream>>>(x_k, WksF, bks, mask, sbuf);
  k_softmax<<<64, 256, 0, stream>>>(sbuf, smx, sinv);
  dim3 bwg(64, 4);
  k_bwsum<<<bwg, 256, 0, stream>>>(x_k, sbuf, smx, sinv, part);
  k_gkrw<<<64, 256, 0, stream>>>(part, WkT, bk, gq, Wr, bv, br, WrgT, bcomb);

  // ---- fold gk into combined V weight ----
  dim3 wcg(8, 64);
  k_wcomb<<<wcg, 256, 0, stream>>>(WrgT, WvN, WcombT);

  // ---- A = x_v @ Wcomb_n + bcomb_n + q  (v never materialized) ----
  k_gemm<1, 0, 1><<<ggrid, 256, 0, stream>>>(xvb, WcombT, bcomb, (void*)abuf,
                                             nullptr, nullptr, nullptr, qbf,
                                             MTOK, DMODEL, DMODEL);

  // ---- final projection ----
  k_gemm<0, 0, 0><<<ggrid, 256, 0, stream>>>(abuf, WfT, bfc, d_out, nullptr,
                                             nullptr, nullptr, nullptr,
                                             MTOK, DMODEL, DMODEL);
}

// Round 17
// 271.196 us; speedup vs baseline: 1.3326x; 1.3326x over previous
//
#include <hip/hip_runtime.h>

typedef __bf16 bf16x8 __attribute__((ext_vector_type(8)));
typedef float f32x4 __attribute__((ext_vector_type(4)));
typedef unsigned int u32x4 __attribute__((ext_vector_type(4)));
typedef unsigned short u16x4 __attribute__((ext_vector_type(4)));
typedef unsigned short u16x8 __attribute__((ext_vector_type(8)));

#define SEQ_T 4096
#define DMODEL 1024
#define HEADS 16
#define DKH 64
#define MTOK 16384  // N*T rows

#define AS1 __attribute__((address_space(1)))
#define AS3 __attribute__((address_space(3)))

__device__ __forceinline__ unsigned short f2bf(float f) {
  unsigned u = __builtin_bit_cast(unsigned int, f);
  u += 0x7FFFu + ((u >> 16) & 1u);
  return (unsigned short)(u >> 16);
}
__device__ __forceinline__ float bf2f(unsigned short h) {
  unsigned u = ((unsigned)h) << 16;
  return __builtin_bit_cast(float, u);
}
__device__ __forceinline__ void gload16(const unsigned short* g, unsigned short* l) {
  __builtin_amdgcn_global_load_lds((const AS1 unsigned int*)(g),
                                   (AS3 unsigned int*)(l), 16, 0, 0);
}

// ---- fp32 -> bf16, coalesced: 16B/lane loads, 8B/lane stores ----
// block handles 2048 elems: thread t -> elems [b+t*4, b+t*4+4) and +1024.
__device__ __forceinline__ void cvt_block(const float* __restrict__ x,
                                          unsigned short* __restrict__ y,
                                          size_t b, int tid) {
  f32x4 a0 = *(const f32x4*)(x + b + tid * 4);
  f32x4 a1 = *(const f32x4*)(x + b + 1024 + tid * 4);
  u16x4 o0, o1;
#pragma unroll
  for (int j = 0; j < 4; ++j) {
    o0[j] = f2bf(a0[j]);
    o1[j] = f2bf(a1[j]);
  }
  *(u16x4*)(y + b + tid * 4) = o0;
  *(u16x4*)(y + b + 1024 + tid * 4) = o1;
}

__global__ void __launch_bounds__(256) k_cvt(const float* __restrict__ x,
                                             unsigned short* __restrict__ y) {
  cvt_block(x, y, (size_t)blockIdx.x * 2048, threadIdx.x);
}

// ---- upfront cvt of x_q/x_k/x_v (3 x 16M elems, 3*8192 blocks) ----
__global__ void __launch_bounds__(256) k_cvt3(const float* __restrict__ xq,
                                              const float* __restrict__ xk,
                                              const float* __restrict__ xv,
                                              unsigned short* __restrict__ oq,
                                              unsigned short* __restrict__ ok,
                                              unsigned short* __restrict__ ov) {
  const int which = blockIdx.x >> 13;
  const float* x = which == 0 ? xq : (which == 1 ? xk : xv);
  unsigned short* y = which == 0 ? oq : (which == 1 ? ok : ov);
  cvt_block(x, y, (size_t)(blockIdx.x & 8191) * 2048, threadIdx.x);
}

// ---------------- W (K x N) fp32 -> Wt (N x K) bf16 ----------------
__global__ void __launch_bounds__(256) k_wtrans(const float* __restrict__ W,
                                                unsigned short* __restrict__ Wt,
                                                int K, int N) {
  __shared__ float tile[32][33];
  int bn = blockIdx.x * 32, bk = blockIdx.y * 32;
  int tx = threadIdx.x, ty = threadIdx.y;  // 32 x 8
#pragma unroll
  for (int j = 0; j < 32; j += 8)
    tile[ty + j][tx] = W[(size_t)(bk + ty + j) * N + bn + tx];
  __syncthreads();
#pragma unroll
  for (int j = 0; j < 32; j += 8)
    Wt[(size_t)(bn + ty + j) * K + bk + tx] = f2bf(tile[tx][ty + j]);
}

// ------- bf16 NT GEMM (R2 core + BK=64 swizzle + chunked XCD remap) -------
// C = A*Bt^T + bias.  SCORE=1: fused alpha scores.  FUSEA=1: per-n Bt/bias
// + fused q-add.  Chunked XCD remap: XCD x owns 16 consecutive row-panels x
// all 8 column blocks -> A-panel + B resident in its 4MB L2.
#define BM 128
#define BN 128
#define BK 64

template <int OBF, int SCORE, int FUSEA>
__global__ void __launch_bounds__(256, 2)
k_gemm(const unsigned short* __restrict__ A, const unsigned short* __restrict__ Bt,
       const float* __restrict__ bias, void* __restrict__ C,
       const int* __restrict__ mask, const float* __restrict__ swt,
       float* __restrict__ sbuf, const unsigned short* __restrict__ qadd,
       int M, int N, int K) {
  __shared__ unsigned short As[BM * BK];
  __shared__ unsigned short Bs[BN * BK];
  const int tid = threadIdx.x;
  const int lane = tid & 63, wid = tid >> 6;
  const int wr = wid >> 1, wc = wid & 1;
  const int l15 = lane & 15, l4 = lane >> 4;

  // bijective chunked XCD remap (nwg = 8*128 = 1024, %8 == 0)
  const int nwg = gridDim.x * gridDim.y;
  const int flat = blockIdx.x + blockIdx.y * gridDim.x;
  const int rm = (flat & 7) * (nwg >> 3) + (flat >> 3);
  const int bx = rm % gridDim.x, by = rm / gridDim.x;
  const int bm = by * BM, bn = bx * BN;

  const unsigned short* Btn = FUSEA ? Bt + ((size_t)(bm >> 12) << 20) : Bt;
  const float* biasn = FUSEA ? bias + ((bm >> 12) << 10) : bias;

  f32x4 acc[4][4];
#pragma unroll
  for (int i = 0; i < 4; ++i)
#pragma unroll
    for (int j = 0; j < 4; ++j)
#pragma unroll
      for (int e = 0; e < 4; ++e) acc[i][j][e] = 0.f;

  // staging: one gload16 covers 8 rows x 128B; lane l -> row +(l>>3),
  // source chunk (l&7)^(l>>3) (pre-swizzled; LDS slot is linear l&7).
  const int sgr = lane >> 3;
  const int sgc = (lane & 7) ^ sgr;

  for (int kt = 0; kt < K; kt += BK) {
    __syncthreads();  // previous tile consumed
#pragma unroll
    for (int j = 0; j < 4; ++j) {
      int rb = wid * 32 + j * 8;
      gload16(A + (size_t)(bm + rb + sgr) * K + kt + sgc * 8, As + rb * BK);
    }
#pragma unroll
    for (int j = 0; j < 4; ++j) {
      int rb = wid * 32 + j * 8;
      gload16(Btn + (size_t)(bn + rb + sgr) * K + kt + sgc * 8, Bs + rb * BK);
    }
    __syncthreads();  // drain -> tile resident
#pragma unroll
    for (int kh = 0; kh < 2; ++kh) {
      bf16x8 af[4], bfr[4];
#pragma unroll
      for (int m = 0; m < 4; ++m) {
        int ra = wr * 64 + m * 16 + l15;
        int sl = (kh * 4 + l4) ^ (ra & 7);
        af[m] = *(const bf16x8*)(As + ra * BK + sl * 8);
      }
#pragma unroll
      for (int n = 0; n < 4; ++n) {
        int rb = wc * 64 + n * 16 + l15;
        int sl = (kh * 4 + l4) ^ (rb & 7);
        bfr[n] = *(const bf16x8*)(Bs + rb * BK + sl * 8);
      }
#pragma unroll
      for (int m = 0; m < 4; ++m)
#pragma unroll
        for (int n = 0; n < 4; ++n)
          acc[m][n] = __builtin_amdgcn_mfma_f32_16x16x32_bf16(af[m], bfr[n],
                                                              acc[m][n], 0, 0, 0);
    }
  }

  const int crow = bm + wr * 64 + l4 * 4;
  const int ccol = bn + wc * 64 + l15;

  float pacc[4][4];
  const float* wrow = nullptr;
  if (SCORE == 1) wrow = swt;
  if (SCORE) {
#pragma unroll
    for (int m = 0; m < 4; ++m)
#pragma unroll
      for (int e = 0; e < 4; ++e) pacc[m][e] = 0.f;
  }

#pragma unroll
  for (int m = 0; m < 4; ++m)
#pragma unroll
    for (int n = 0; n < 4; ++n) {
      int c = ccol + n * 16;
      float bj = biasn[c];
      float wg = SCORE ? wrow[n * 16 + l15] : 0.f;
#pragma unroll
      for (int e = 0; e < 4; ++e) {
        int r = crow + m * 16 + e;
        float v = acc[m][n][e] + bj;
        if (FUSEA) v += bf2f(qadd[(size_t)r * N + c]);
        if (SCORE) pacc[m][e] += v * wg;
        if (OBF)
          ((unsigned short*)C)[(size_t)r * N + c] = f2bf(v);
        else
          ((float*)C)[(size_t)r * N + c] = v;
      }
    }

  if (SCORE) {
#pragma unroll
    for (int m = 0; m < 4; ++m)
#pragma unroll
      for (int e = 0; e < 4; ++e) {
        float p = pacc[m][e];
        p += __shfl_xor(p, 1);
        p += __shfl_xor(p, 2);
        p += __shfl_xor(p, 4);
        p += __shfl_xor(p, 8);
        if (l15 == 0) {
          int r = crow + m * 16 + e;
          int t = r & (SEQ_T - 1), n = r >> 12;
          float sc = p * 0.125f;
          if (mask[n * SEQ_T + t] == 0) sc = -3.0e38f;
          sbuf[((size_t)n * HEADS + bx * 2 + wc) * SEQ_T + t] = sc;
        }
      }
  }
}

// ---- per-(n,h) softmax stats over T=4096 (merged max+sum, 64 blocks) ----
__global__ void __launch_bounds__(256) k_softmax(const float* __restrict__ s,
                                                 float* __restrict__ mxo,
                                                 float* __restrict__ invo) {
  __shared__ float red[4];
  const int tid = threadIdx.x, lane = tid & 63, wid = tid >> 6;
  const float* sb = s + (size_t)blockIdx.x * SEQ_T;
  float m = -3.4e38f;
  for (int t = tid; t < SEQ_T; t += 256) m = fmaxf(m, sb[t]);
#pragma unroll
  for (int o = 1; o < 64; o <<= 1) m = fmaxf(m, __shfl_xor(m, o));
  if (lane == 0) red[wid] = m;
  __syncthreads();
  m = fmaxf(fmaxf(red[0], red[1]), fmaxf(red[2], red[3]));
  __syncthreads();
  float sum = 0.f;
  for (int t = tid; t < SEQ_T; t += 256) sum += __expf(sb[t] - m);
#pragma unroll
  for (int o = 1; o < 64; o <<= 1) sum += __shfl_xor(sum, o);
  if (lane == 0) red[wid] = sum;
  __syncthreads();
  if (tid == 0) {
    mxo[blockIdx.x] = m;
    invo[blockIdx.x] = 1.f / (red[0] + red[1] + red[2] + red[3]);
  }
}

// ---- alpha weighted sum: pbuf[nh,chunk,:] = sum_t w[t]*q[n,t,h,:] ----
__global__ void __launch_bounds__(256) k_wsum(const unsigned short* __restrict__ X,
                                              const float* __restrict__ s,
                                              const float* __restrict__ mxv,
                                              const float* __restrict__ invv,
                                              float* __restrict__ pbuf) {
  __shared__ float part[16][64];
  const int nh = blockIdx.x >> 4, chunk = blockIdx.x & 15;
  const int n = nh >> 4, h = nh & 15;
  const int tid = threadIdx.x, lane = tid & 63, wid = tid >> 6;
  const int tsub = lane >> 4, dl = lane & 15;
  const float mx = mxv[nh], inv = invv[nh];
  const float* sb = s + (size_t)nh * SEQ_T + chunk * 256;
  const size_t base = ((size_t)n * SEQ_T + chunk * 256) * DMODEL + h * DKH + dl * 4;
  f32x4 acc = {0.f, 0.f, 0.f, 0.f};
  for (int t = wid * 4 + tsub; t < 256; t += 16) {
    float w = __expf(sb[t] - mx) * inv;
    u16x4 xv = *(const u16x4*)(X + base + (size_t)t * DMODEL);
    acc[0] += w * bf2f(xv[0]);
    acc[1] += w * bf2f(xv[1]);
    acc[2] += w * bf2f(xv[2]);
    acc[3] += w * bf2f(xv[3]);
  }
  int g = wid * 4 + tsub;
#pragma unroll
  for (int e = 0; e < 4; ++e) part[g][dl * 4 + e] = acc[e];
  __syncthreads();
  if (tid < 64) {
    float v = 0.f;
#pragma unroll
    for (int gg = 0; gg < 16; ++gg) v += part[gg][tid];
    pbuf[(size_t)blockIdx.x * 64 + tid] = v;
  }
}

// ---- merged fin+wks+bks: gq from pbuf; wv=gq*bw; WksT=Wk·wv; bks=bk·wv ----
__global__ void __launch_bounds__(256) k_wksb(const float* __restrict__ Wk,
                                              const float* __restrict__ bk,
                                              const float* __restrict__ pbuf,
                                              const float* __restrict__ bw,
                                              float* __restrict__ gq,
                                              unsigned short* __restrict__ WksT,
                                              float* __restrict__ bks) {
  const int nh = blockIdx.x, tid = threadIdx.x;
  const int n = nh >> 4, h = nh & 15;
  __shared__ float wvs[64];
  if (tid < 64) {
    float v = 0.f;
#pragma unroll
    for (int c = 0; c < 16; ++c) v += pbuf[((size_t)nh * 16 + c) * 64 + tid];
    gq[(size_t)nh * 64 + tid] = v;
    wvs[tid] = v * bw[tid];
  }
  __syncthreads();
  int c0 = tid * 4;
  u16x4 o;
#pragma unroll
  for (int i = 0; i < 4; ++i) {
    int c = c0 + i;
    const float* wr = Wk + (size_t)c * DMODEL + h * DKH;
    float acc = 0.f;
#pragma unroll
    for (int dd = 0; dd < 64; dd += 4) {
      f32x4 w4 = *(const f32x4*)(wr + dd);
      acc += w4[0] * wvs[dd] + w4[1] * wvs[dd + 1] + w4[2] * wvs[dd + 2] +
             w4[3] * wvs[dd + 3];
    }
    o[i] = f2bf(acc);
  }
  *(u16x4*)(WksT + (size_t)n * 16 * DMODEL + (size_t)h * DMODEL + c0) = o;
  if (tid < 64) {
    float p = bk[h * 64 + tid] * wvs[tid];
#pragma unroll
    for (int ofs = 1; ofs < 64; ofs <<= 1) p += __shfl_xor(p, ofs);
    if (tid == 0) bks[nh] = p;
  }
}

// ---- beta scores via skinny MFMA: s[nh][t] = (x_k[t]·WksT[n][h]+bks)*scale ----
__global__ void __launch_bounds__(128) k_score(const unsigned short* __restrict__ xk,
                                               const unsigned short* __restrict__ WksT,
                                               const float* __restrict__ bks,
                                               const int* __restrict__ mask,
                                               float* __restrict__ sbuf) {
  __shared__ unsigned short Xs[64 * 32];
  __shared__ unsigned short Ws[16 * 32];
  const int tid = threadIdx.x, lane = tid & 63, wid = tid >> 6;
  const int l15 = lane & 15, l4 = lane >> 4;
  const int bm = blockIdx.x * 64;
  const int n = bm >> 12;
  const unsigned short* Wn = WksT + (size_t)n * 16 * DMODEL;

  f32x4 acc[2];
#pragma unroll
  for (int m = 0; m < 2; ++m)
#pragma unroll
    for (int e = 0; e < 4; ++e) acc[m][e] = 0.f;

  const int srow = lane >> 2, scol = (lane & 3) * 8;
  for (int kt = 0; kt < DMODEL; kt += 32) {
    __syncthreads();
#pragma unroll
    for (int j = 0; j < 2; ++j) {
      int rb = wid * 32 + j * 16;
      gload16(xk + (size_t)(bm + rb + srow) * DMODEL + kt + scol, Xs + rb * 32);
    }
    if (wid == 0) gload16(Wn + (size_t)srow * DMODEL + kt + scol, Ws);
    __syncthreads();
    bf16x8 bfr = *(const bf16x8*)(Ws + l15 * 32 + l4 * 8);
#pragma unroll
    for (int m = 0; m < 2; ++m) {
      bf16x8 af = *(const bf16x8*)(Xs + (wid * 32 + m * 16 + l15) * 32 + l4 * 8);
      acc[m] = __builtin_amdgcn_mfma_f32_16x16x32_bf16(af, bfr, acc[m], 0, 0, 0);
    }
  }
  const int h = l15;
  const float bh = bks[n * 16 + h];
#pragma unroll
  for (int m = 0; m < 2; ++m)
#pragma unroll
    for (int e = 0; e < 4; ++e) {
      int r = bm + wid * 32 + m * 16 + l4 * 4 + e;
      int t = r & (SEQ_T - 1);
      float sc = (acc[m][e] + bh) * 0.125f;
      if (mask[n * SEQ_T + t] == 0) sc = -3.0e38f;
      sbuf[((size_t)n * HEADS + h) * SEQ_T + t] = sc;
    }
}

// ---- beta-weighted pooling of x_k (bf16): part[(n*64+tc)][h][c] ----
__global__ void __launch_bounds__(256) k_bwsum(const unsigned short* __restrict__ xk,
                                               const float* __restrict__ s,
                                               const float* __restrict__ smx,
                                               const float* __restrict__ sinv,
                                               float* __restrict__ part) {
  __shared__ float eb[16][64];
  const int tc = blockIdx.x, n = blockIdx.y, tid = threadIdx.x;
#pragma unroll
  for (int i = 0; i < 4; ++i) {
    int idx = i * 256 + tid;
    int h = idx >> 6, t = idx & 63;
    int nh = n * 16 + h;
    eb[h][t] = __expf(s[(size_t)nh * SEQ_T + tc * 64 + t] - smx[nh]) * sinv[nh];
  }
  __syncthreads();
  const int c0 = tid * 4;
  f32x4 acc[16];
#pragma unroll
  for (int h = 0; h < 16; ++h)
#pragma unroll
    for (int e = 0; e < 4; ++e) acc[h][e] = 0.f;
  const unsigned short* xb = xk + ((size_t)n * SEQ_T + tc * 64) * DMODEL + c0;
  for (int t = 0; t < 64; ++t) {
    u16x4 xr = *(const u16x4*)(xb + (size_t)t * DMODEL);
    float x0 = bf2f(xr[0]), x1 = bf2f(xr[1]), x2 = bf2f(xr[2]), x3 = bf2f(xr[3]);
#pragma unroll
    for (int h = 0; h < 16; ++h) {
      float w = eb[h][t];
      acc[h][0] += w * x0;
      acc[h][1] += w * x1;
      acc[h][2] += w * x2;
      acc[h][3] += w * x3;
    }
  }
#pragma unroll
  for (int h = 0; h < 16; ++h)
    *(f32x4*)(part + (((size_t)(n * 64 + tc)) * 16 + h) * DMODEL + c0) = acc[h];
}

// ---- merged gkr+wrgb: pooled=Σpart; gk=gq*(pooled·WkT+bk) (smem);
//      WrgT[nh][d][dd]=gk[dd]*Wr[dd][d]; bcomb=bv·Wrg+br ----
__global__ void __launch_bounds__(256) k_gkrw(const float* __restrict__ part,
                                              const unsigned short* __restrict__ WkT,
                                              const float* __restrict__ bk,
                                              const float* __restrict__ gq,
                                              const float* __restrict__ Wr,
                                              const float* __restrict__ bv,
                                              const float* __restrict__ br,
                                              unsigned short* __restrict__ WrgT,
                                              float* __restrict__ bcomb) {
  __shared__ float pl[DMODEL];
  __shared__ float gks[64];
  __shared__ float wl[4096];
  const int nh = blockIdx.x, tid = threadIdx.x;
  const int n = nh >> 4, h = nh & 15;
  const int c0 = tid * 4;
  f32x4 a4 = {0.f, 0.f, 0.f, 0.f};
  for (int tc = 0; tc < 64; ++tc) {
    f32x4 p = *(const f32x4*)(part + (((size_t)(n * 64 + tc)) * 16 + h) * DMODEL + c0);
    a4[0] += p[0]; a4[1] += p[1]; a4[2] += p[2]; a4[3] += p[3];
  }
#pragma unroll
  for (int e = 0; e < 4; ++e) pl[c0 + e] = a4[e];
  __syncthreads();
  if (tid < 64) {
    const unsigned short* wr = WkT + (size_t)(h * 64 + tid) * DMODEL;
    float acc = 0.f;
    for (int c = 0; c < DMODEL; c += 8) {
      u16x8 w = *(const u16x8*)(wr + c);
#pragma unroll
      for (int j = 0; j < 8; ++j) acc += pl[c + j] * bf2f(w[j]);
    }
    gks[tid] = gq[(size_t)nh * 64 + tid] * (acc + bk[h * 64 + tid]);
  }
  __syncthreads();
#pragma unroll
  for (int i = 0; i < 16; ++i) {
    int idx = i * 256 + tid;
    int d = idx >> 6, dd = idx & 63;
    float v = gks[dd] * Wr[dd * 64 + d];
    wl[idx] = v;
    WrgT[(size_t)nh * 4096 + idx] = f2bf(v);
  }
  __syncthreads();
  if (tid < 64) {
    float acc = br[tid];
#pragma unroll
    for (int dd = 0; dd < 64; ++dd) acc += bv[h * 64 + dd] * wl[tid * 64 + dd];
    bcomb[(size_t)n * DMODEL + h * 64 + tid] = acc;
  }
}

// ---- WcombT[n][h*64+d][r] = sum_dd WrgT[nh][d][dd] * WvN[r][h*64+dd] ----
#define LDW 72
__global__ void __launch_bounds__(256) k_wcomb(const unsigned short* __restrict__ WrgT,
                                               const unsigned short* __restrict__ WvN,
                                               unsigned short* __restrict__ WcombT) {
  __shared__ unsigned short Wg[64 * LDW];
  __shared__ unsigned short Vv[128 * LDW];
  const int rc = blockIdx.x, nh = blockIdx.y;
  const int n = nh >> 4, h = nh & 15;
  const int tid = threadIdx.x, lane = tid & 63, wid = tid >> 6;
  const int l15 = lane & 15, l4 = lane >> 4;
#pragma unroll
  for (int i = 0; i < 2; ++i) {
    int v = i * 256 + tid;
    int d = v >> 3, k8 = v & 7;
    *(u16x8*)(Wg + d * LDW + k8 * 8) =
        *(const u16x8*)(WrgT + (size_t)nh * 4096 + d * 64 + k8 * 8);
  }
#pragma unroll
  for (int i = 0; i < 4; ++i) {
    int v = i * 256 + tid;
    int r = v >> 3, k8 = v & 7;
    *(u16x8*)(Vv + r * LDW + k8 * 8) =
        *(const u16x8*)(WvN + (size_t)(rc * 128 + r) * DMODEL + h * 64 + k8 * 8);
  }
  __syncthreads();
  f32x4 acc[8];
#pragma unroll
  for (int ct = 0; ct < 8; ++ct)
#pragma unroll
    for (int e = 0; e < 4; ++e) acc[ct][e] = 0.f;
#pragma unroll
  for (int ks = 0; ks < 2; ++ks) {
    bf16x8 af = *(const bf16x8*)(Wg + (wid * 16 + l15) * LDW + ks * 32 + l4 * 8);
#pragma unroll
    for (int ct = 0; ct < 8; ++ct) {
      bf16x8 bf = *(const bf16x8*)(Vv + (ct * 16 + l15) * LDW + ks * 32 + l4 * 8);
      acc[ct] = __builtin_amdgcn_mfma_f32_16x16x32_bf16(af, bf, acc[ct], 0, 0, 0);
    }
  }
  unsigned short* out = WcombT + ((size_t)n << 20);
#pragma unroll
  for (int ct = 0; ct < 8; ++ct)
#pragma unroll
    for (int e = 0; e < 4; ++e) {
      int d = h * 64 + wid * 16 + l4 * 4 + e;
      int r = rc * 128 + ct * 16 + l15;
      out[(size_t)d * DMODEL + r] = f2bf(acc[ct][e]);
    }
}

extern "C" void kernel_launch(void* const* d_in, const int* in_sizes, int n_in,
                              void* d_out, int out_size, void* d_ws, size_t ws_size,
                              hipStream_t stream) {
  const float* x_k = (const float*)d_in[0];
  const float* x_v = (const float*)d_in[1];
  const float* x_q = (const float*)d_in[2];
  const int* mask = (const int*)d_in[3];
  const float* Wk = (const float*)d_in[4];
  const float* bk = (const float*)d_in[5];
  const float* Wv = (const float*)d_in[6];
  const float* bv = (const float*)d_in[7];
  const float* Wq = (const float*)d_in[8];
  const float* bq = (const float*)d_in[9];
  const float* alpha_w = (const float*)d_in[10];
  const float* beta_w = (const float*)d_in[11];
  const float* Wr = (const float*)d_in[12];
  const float* br = (const float*)d_in[13];
  const float* Wfc = (const float*)d_in[14];
  const float* bfc = (const float*)d_in[15];

  // d_out layout during pipeline: [0:32MB) q bf16 (written by Q GEMM),
  // [32:64MB) x_v bf16 (written by cvt3).  Both dead before final GEMM write.
  unsigned short* qbf = (unsigned short*)d_out;
  unsigned short* xvb = (unsigned short*)d_out + (size_t)MTOK * DMODEL;

  char* ws = (char*)d_ws;
  const size_t MB = 1024 * 1024;
  unsigned short* xst = (unsigned short*)(ws);                 // 32 MB: x_q bf16
  unsigned short* abuf = (unsigned short*)(ws + 32 * MB);      // 32 MB: x_k bf16, later A
  unsigned short* WqT = (unsigned short*)(ws + 64 * MB);       // 2 MB
  unsigned short* WkT = WqT + (size_t)DMODEL * DMODEL;         // 2 MB
  unsigned short* WfT = WkT + (size_t)DMODEL * DMODEL;         // 2 MB
  unsigned short* WvN = WfT + (size_t)DMODEL * DMODEL;         // 2 MB
  unsigned short* WcombT = WvN + (size_t)DMODEL * DMODEL;      // 8 MB
  unsigned short* WrgT = WcombT + (size_t)4 * DMODEL * DMODEL; // 512 KB
  unsigned short* WksT = WrgT + (size_t)64 * 4096;             // 128 KB
  float* part = (float*)(WksT + (size_t)4 * 16 * DMODEL);      // 16 MB
  float* sbuf = part + (size_t)256 * 16 * DMODEL;              // 1 MB
  float* pbuf = sbuf + (size_t)64 * SEQ_T;                     // 256 KB
  float* smx = pbuf + 1024 * 64;
  float* sinv = smx + 64;
  float* gq = sinv + 64;
  float* bks = gq + 4096;
  float* bcomb = bks + 64;

  dim3 tb(32, 8);
  dim3 tg(DMODEL / 32, DMODEL / 32);
  k_wtrans<<<tg, tb, 0, stream>>>(Wq, WqT, DMODEL, DMODEL);
  k_wtrans<<<tg, tb, 0, stream>>>(Wk, WkT, DMODEL, DMODEL);
  k_wtrans<<<tg, tb, 0, stream>>>(Wfc, WfT, DMODEL, DMODEL);
  k_cvt<<<512, 256, 0, stream>>>(Wv, WvN);

  // upfront conversions: x_q -> xst, x_k -> abuf, x_v -> d_out upper half
  k_cvt3<<<3 * 8192, 256, 0, stream>>>(x_q, x_k, x_v, xst, abuf, xvb);

  dim3 ggrid(DMODEL / BN, MTOK / BM);  // (8, 128)

  // ---- Q projection (+fused alpha scores), q -> bf16 in d_out ----
  k_gemm<1, 1, 0><<<ggrid, 256, 0, stream>>>(xst, WqT, bq, (void*)qbf, mask,
                                             alpha_w, sbuf, nullptr,
                                             MTOK, DMODEL, DMODEL);
  // alpha pooling -> gq; then WksT/bks (merged)
  k_softmax<<<64, 256, 0, stream>>>(sbuf, smx, sinv);
  k_wsum<<<1024, 256, 0, stream>>>(qbf, sbuf, smx, sinv, pbuf);
  k_wksb<<<64, 256, 0, stream>>>(Wk, bk, pbuf, beta_w, gq, WksT, bks);

  // ---- K path (folded; k never materialized) ----
  k_score<<<MTOK / 64, 128, 0, stream>>>(abuf, WksT, bks, mask, sbuf);
  k_softmax<<<64, 256, 0, stream>>>(sbuf, smx, sinv);
  dim3 bwg(64, 4);
  k_bwsum<<<bwg, 256, 0, stream>>>(abuf, sbuf, smx, sinv, part);
  k_gkrw<<<64, 256, 0, stream>>>(part, WkT, bk, gq, Wr, bv, br, WrgT, bcomb);

  // ---- fold gk into combined V weight ----
  dim3 wcg(8, 64);
  k_wcomb<<<wcg, 256, 0, stream>>>(WrgT, WvN, WcombT);

  // ---- A = x_v @ Wcomb_n + bcomb_n + q  (v never materialized) ----
  k_gemm<1, 0, 1><<<ggrid, 256, 0, stream>>>(xvb, WcombT, bcomb, (void*)abuf,
                                             nullptr, nullptr, nullptr, qbf,
                                             MTOK, DMODEL, DMODEL);

  // ---- final projection ----
  k_gemm<0, 0, 0><<<ggrid, 256, 0, stream>>>(abuf, WfT, bfc, d_out, nullptr,
                                             nullptr, nullptr, nullptr,
                                             MTOK, DMODEL, DMODEL);
}